// Round 1
// baseline (27.965 us; speedup 1.0000x reference)
//
#include <hip/hip_runtime.h>
#include <math.h>

#define NSAMP 32
#define HW 512
#define PW 128
#define POOLED_PER_SAMPLE (PW * PW)       // 16384
#define BLOCKS_PER_SAMPLE 64              // 16384 / 256
#define NACC 14

// acc layout per block partial:
// 0 bce_sum  1 mask_cnt  2 intersection  3 label_sum
// 4 S_v  5 S_h  6 S_l  7 S_vv  8 S_hh  9 S_ll  10 S_vh  11 S_vl  12 S_hl  13 S_vhl

__global__ __launch_bounds__(256) void covloss_main(
    const float* __restrict__ logits, const float* __restrict__ labels,
    const float* __restrict__ v_att,  const float* __restrict__ h_att,
    float* __restrict__ part /* [NSAMP*BLOCKS_PER_SAMPLE][NACC] */)
{
    const int n    = blockIdx.x / BLOCKS_PER_SAMPLE;
    const int pidx = (blockIdx.x % BLOCKS_PER_SAMPLE) * 256 + threadIdx.x;
    const int pr   = pidx >> 7;          // pooled row  0..127
    const int pc   = pidx & 127;         // pooled col  0..127

    const float* lg = logits + (size_t)n * HW * HW;
    const float* lb = labels + (size_t)n * HW * HW;

    float bce = 0.f, cnt = 0.f, inter = 0.f, lsum = 0.f, lpool = 0.f;

#pragma unroll
    for (int i = 0; i < 4; ++i) {
        const int row = 4 * pr + i;
        const float4 p4 = *(const float4*)(lg + (size_t)row * HW + 4 * pc);
        const float4 y4 = *(const float4*)(lb + (size_t)row * HW + 4 * pc);
        const float pv[4] = {p4.x, p4.y, p4.z, p4.w};
        const float yv[4] = {y4.x, y4.y, y4.z, y4.w};
#pragma unroll
        for (int j = 0; j < 4; ++j) {
            const float p = pv[j], y = yv[j];
            bce += y * __logf(p) + (1.f - y) * __logf(1.f - p);
            const float m = (p > 0.4f) ? 1.f : 0.f;
            cnt  += m;
            inter += m * y;
            lsum += y;
            lpool += y;
        }
    }

    const float l = lpool * (1.f / 16.f);   // 4x4 average pool == mean of 2x2 means
    const size_t vi = (size_t)n * POOLED_PER_SAMPLE + pidx;
    const float v = v_att[vi];
    const float h = h_att[vi];

    float vals[NACC] = { bce, cnt, inter, lsum,
                         v, h, l,
                         v * v, h * h, l * l,
                         v * h, v * l, h * l, v * h * l };

    // 64-lane wave reduce
#pragma unroll
    for (int k = 0; k < NACC; ++k) {
        float x = vals[k];
#pragma unroll
        for (int off = 32; off > 0; off >>= 1)
            x += __shfl_down(x, off, 64);
        vals[k] = x;
    }

    __shared__ float sh[4][NACC];
    const int lane = threadIdx.x & 63;
    const int wave = threadIdx.x >> 6;
    if (lane == 0) {
#pragma unroll
        for (int k = 0; k < NACC; ++k) sh[wave][k] = vals[k];
    }
    __syncthreads();
    if (threadIdx.x == 0) {
        float* dst = part + (size_t)blockIdx.x * NACC;
#pragma unroll
        for (int k = 0; k < NACC; ++k)
            dst[k] = sh[0][k] + sh[1][k] + sh[2][k] + sh[3][k];
    }
}

__global__ __launch_bounds__(256) void covloss_finalize(
    const float* __restrict__ part, float* __restrict__ out)
{
    const int t   = threadIdx.x;
    const int s   = t >> 3;   // sample 0..31
    const int sub = t & 7;    // 8 threads per sample

    double a[NACC];
#pragma unroll
    for (int k = 0; k < NACC; ++k) a[k] = 0.0;

    for (int b = sub; b < BLOCKS_PER_SAMPLE; b += 8) {
        const float* p = part + (size_t)(s * BLOCKS_PER_SAMPLE + b) * NACC;
#pragma unroll
        for (int k = 0; k < NACC; ++k) a[k] += (double)p[k];
    }

    // reduce across the 8 threads of this sample (lanes 8s..8s+7 in a wave)
#pragma unroll
    for (int off = 4; off > 0; off >>= 1) {
#pragma unroll
        for (int k = 0; k < NACC; ++k)
            a[k] += __shfl_down(a[k], off, 8);
    }

    __shared__ double sh_bce[NSAMP], sh_dice[NSAMP], sh_cor[NSAMP];
    if (sub == 0) {
        const double n = (double)POOLED_PER_SAMPLE;
        const double cvv = a[7] - a[4] * a[4] / n;
        const double chh = a[8] - a[5] * a[5] / n;
        const double cll = a[9] - a[6] * a[6] / n;
        const double num = a[13]
            - (a[4] * a[12] + a[5] * a[11] + a[6] * a[10]) / n
            + 2.0 * a[4] * a[5] * a[6] / (n * n);
        const double den = sqrt(cvv * chh * cll);
        sh_cor[s]  = num / den;
        sh_dice[s] = 2.0 * (a[2] + 1.0) / (a[1] + a[3] + 1.0);
        sh_bce[s]  = a[0];
    }
    __syncthreads();
    if (t == 0) {
        double bce = 0.0, dsum = 0.0, csum = 0.0;
#pragma unroll
        for (int i = 0; i < NSAMP; ++i) {
            bce  += sh_bce[i];
            dsum += sh_dice[i];
            csum += sh_cor[i];
        }
        const double bceloss  = -bce / ((double)NSAMP * HW * HW);
        const double diceloss = 1.0 - dsum / (double)NSAMP;
        const double corloss  = -csum / (double)NSAMP;
        out[0] = (float)(0.2 * bceloss + 0.3 * diceloss + 0.5 * corloss);
    }
}

extern "C" void kernel_launch(void* const* d_in, const int* in_sizes, int n_in,
                              void* d_out, int out_size, void* d_ws, size_t ws_size,
                              hipStream_t stream) {
    const float* logits = (const float*)d_in[0];
    const float* labels = (const float*)d_in[1];
    const float* v_att  = (const float*)d_in[2];
    const float* h_att  = (const float*)d_in[3];
    float* out  = (float*)d_out;
    float* part = (float*)d_ws;   // NSAMP*BLOCKS_PER_SAMPLE*NACC floats = 112 KB

    covloss_main<<<NSAMP * BLOCKS_PER_SAMPLE, 256, 0, stream>>>(
        logits, labels, v_att, h_att, part);
    covloss_finalize<<<1, 256, 0, stream>>>(part, out);
}